// Round 12
// baseline (172.672 us; speedup 1.0000x reference)
//
#include <hip/hip_runtime.h>
#include <math.h>

#define B_ 8
#define T_ 2048
#define D_ 1024
#define H_ 128
#define BT (B_ * T_)

typedef short bf16x8 __attribute__((ext_vector_type(8)));
typedef float f32x4 __attribute__((ext_vector_type(4)));

static constexpr float SCALE = 0.08838834764831845f;   // 1/sqrt(128)
static constexpr float SCALE2 = 0.127517416f;          // SCALE * log2(e)

__device__ inline unsigned short f2b(float f) {
  unsigned int u = __float_as_uint(f);
  u += 0x7FFF + ((u >> 16) & 1);  // RNE
  return (unsigned short)(u >> 16);
}
__device__ inline unsigned int pk2(float a, float b) {
  return (unsigned int)f2b(a) | ((unsigned int)f2b(b) << 16);
}

// global (AS1) -> LDS (AS3) direct 16B copy; dest = wave-uniform base + lane*16
__device__ __forceinline__ void gll16(const void* g, void* l) {
  __builtin_amdgcn_global_load_lds(
      (const __attribute__((address_space(1))) void*)g,
      (__attribute__((address_space(3))) void*)l, 16, 0, 0);
}

// ---------------------------------------------------------------------------
// Setup: W[d][h] fp32 -> Wt[sel][h][d] bf16 through LDS, coalesced stores.
// ---------------------------------------------------------------------------
__global__ __launch_bounds__(256) void wcvt_kernel(
    const float* __restrict__ Wq, const float* __restrict__ Wk,
    const float* __restrict__ Wv, short* __restrict__ Wt) {
  __shared__ short Wls[128 * 72];  // [h][d] bf16, pitch 72
  const int sel = blockIdx.y;
  const float* W = sel == 0 ? Wq : (sel == 1 ? Wk : Wv);
  const int d0 = blockIdx.x * 64;
  const int tid = threadIdx.x;
#pragma unroll
  for (int i = 0; i < 8; ++i) {
    int slot = tid + i * 256;         // 2048 float4 slots: 64 d x 32 h-groups
    int r = slot >> 5, hg = slot & 31;
    float4 w = *(const float4*)(W + (size_t)(d0 + r) * H_ + hg * 4);
    Wls[(hg * 4 + 0) * 72 + r] = (short)f2b(w.x);
    Wls[(hg * 4 + 1) * 72 + r] = (short)f2b(w.y);
    Wls[(hg * 4 + 2) * 72 + r] = (short)f2b(w.z);
    Wls[(hg * 4 + 3) * 72 + r] = (short)f2b(w.w);
  }
  __syncthreads();
  short* dst = Wt + (size_t)sel * D_ * H_;
#pragma unroll
  for (int i = 0; i < 4; ++i) {
    int slot = tid + i * 256;         // 1024 int4 slots: 128 h x 8 d-groups
    int h = slot >> 3, g = slot & 7;
    *(int4*)(dst + (size_t)h * D_ + d0 + g * 8) = *(int4*)&Wls[h * 72 + g * 8];
  }
}

// ---------------------------------------------------------------------------
// Proj v2: issue-early / pack-late X staging. Per stage: barrier -> gll W(s+1)
// -> issue X loads(s+1) -> compute(s) -> pack+ds_write X(s+1). X load latency
// is covered by compute(s); xr is NOT live across any barrier (no spill trap).
// ---------------------------------------------------------------------------
__global__ __launch_bounds__(256) void proj_kernel(
    const float* __restrict__ x, const short* __restrict__ Wt,
    short* __restrict__ qb, short* __restrict__ kb, short* __restrict__ vtb) {
  __shared__ alignas(16) char smem[49152];
  short* Xs0 = (short*)smem;             // [64][64] bf16 swizzled
  short* Xs1 = (short*)(smem + 8192);
  short* Ws0 = (short*)(smem + 16384);   // [128][64] bf16 swizzled
  short* Ws1 = (short*)(smem + 32768);

  const int tid = threadIdx.x;
  const int wave = tid >> 6, lane = tid & 63;
  const int ln = lane & 15, quad = lane >> 4;
  const int mw = wave & 1, nw = wave >> 1;  // wave tile: 32 rows x 64 cols
  const int sel = blockIdx.y;
  const int row0 = blockIdx.x * 64;
  const short* W = Wt + (size_t)sel * (size_t)(D_ * H_);

  f32x4 acc[2][4];
#pragma unroll
  for (int mi = 0; mi < 2; ++mi)
#pragma unroll
    for (int ni = 0; ni < 4; ++ni) acc[mi][ni] = (f32x4){0.f, 0.f, 0.f, 0.f};

  auto stageW = [&](int bf, int k0) {
    short* Ws = bf ? Ws1 : Ws0;
#pragma unroll
    for (int j = 0; j < 4; ++j) {
      const int rbase = wave * 32 + j * 8;
      const int n = rbase + (lane >> 3);
      const int gp = (lane & 7) ^ (n & 7);
      gll16(W + (size_t)n * D_ + k0 + gp * 8, (char*)Ws + rbase * 128);
    }
  };
  auto packX = [&](int bf, const float4* xr) {
    short* Xs = bf ? Xs1 : Xs0;
#pragma unroll
    for (int i = 0; i < 4; ++i) {
      int fid = tid + i * 256;
      int r = fid >> 4, g4 = fid & 15;
      int g = g4 >> 1, half = g4 & 1;
      unsigned int* p = (unsigned int*)&Xs[r * 64 + ((g ^ (r & 7)) * 8) + half * 4];
      p[0] = pk2(xr[i].x, xr[i].y);
      p[1] = pk2(xr[i].z, xr[i].w);
    }
  };

  {  // prologue: stage 0 (synchronous pack is fine once)
    stageW(0, 0);
    float4 xr[4];
#pragma unroll
    for (int i = 0; i < 4; ++i) {
      int fid = tid + i * 256;
      int r = fid >> 4, g4 = fid & 15;
      xr[i] = *(const float4*)(x + (size_t)(row0 + r) * D_ + g4 * 4);
    }
    packX(0, xr);
  }

  for (int s = 0; s < 16; ++s) {
    __syncthreads();  // drains gll W(s) + pack(s) ds_writes
    float4 xr[4];
    const bool pre = (s < 15);
    if (pre) {
      const int k0n = (s + 1) * 64;
      stageW((s + 1) & 1, k0n);
#pragma unroll
      for (int i = 0; i < 4; ++i) {   // issue early...
        int fid = tid + i * 256;
        int r = fid >> 4, g4 = fid & 15;
        xr[i] = *(const float4*)(x + (size_t)(row0 + r) * D_ + k0n + g4 * 4);
      }
    }
    const short* Xs = (s & 1) ? Xs1 : Xs0;
    const short* Ws = (s & 1) ? Ws1 : Ws0;
#pragma unroll
    for (int kk = 0; kk < 2; ++kk) {
      bf16x8 a[2];
#pragma unroll
      for (int mi = 0; mi < 2; ++mi) {
        int r = mw * 32 + mi * 16 + ln;
        a[mi] = *(bf16x8*)&Xs[r * 64 + (((kk * 4 + quad) ^ (r & 7)) * 8)];
      }
#pragma unroll
      for (int ni = 0; ni < 4; ++ni) {
        int n = nw * 64 + ni * 16 + ln;
        bf16x8 bb = *(bf16x8*)&Ws[n * 64 + (((kk * 4 + quad) ^ (n & 7)) * 8)];
#pragma unroll
        for (int mi = 0; mi < 2; ++mi)
          acc[mi][ni] = __builtin_amdgcn_mfma_f32_16x16x32_bf16(a[mi], bb, acc[mi][ni], 0, 0, 0);
      }
    }
    if (pre) packX((s + 1) & 1, xr);  // ...use late (after compute)
  }

  __syncthreads();  // tiles dead; reuse smem for epilogue repack
  short* Cs = (short*)smem;
  if (sel < 2) {
    short* out = sel ? kb : qb;
#pragma unroll
    for (int mi = 0; mi < 2; ++mi)
#pragma unroll
      for (int ni = 0; ni < 4; ++ni)
#pragma unroll
        for (int rr = 0; rr < 4; ++rr)
          Cs[(mw * 32 + mi * 16 + quad * 4 + rr) * 136 + nw * 64 + ni * 16 + ln] =
              (short)f2b(acc[mi][ni][rr]);
    __syncthreads();
#pragma unroll
    for (int i = 0; i < 4; ++i) {
      int slot = tid + i * 256;          // 1024 int4 slots: 64 rows x 16
      int r = slot >> 4, g = slot & 15;
      *(int4*)(out + (size_t)(row0 + r) * H_ + g * 8) = *(int4*)&Cs[r * 136 + g * 8];
    }
  } else {
#pragma unroll
    for (int mi = 0; mi < 2; ++mi)
#pragma unroll
      for (int ni = 0; ni < 4; ++ni)
#pragma unroll
        for (int rr = 0; rr < 4; ++rr)
          Cs[(nw * 64 + ni * 16 + ln) * 72 + mw * 32 + mi * 16 + quad * 4 + rr] =
              (short)f2b(acc[mi][ni][rr]);
    __syncthreads();
    const int b = row0 >> 11, t0 = row0 & 2047;
#pragma unroll
    for (int i = 0; i < 4; ++i) {
      int slot = tid + i * 256;          // 1024 int4 slots: 128 h x 8
      int h = slot >> 3, g = slot & 7;
      *(int4*)(vtb + (size_t)(b * H_ + h) * T_ + t0 + g * 8) = *(int4*)&Cs[h * 72 + g * 8];
    }
  }
}

// ---------------------------------------------------------------------------
// Attention part 1 v2: 128 q/block (4 waves x 32 q). Each wave owns 32
// queries (2 x 16-q subtiles sharing the K-frag reads: 32 S-MFMAs + 32
// PV-MFMAs per chunk). Key-split segments of <=8 chunks; 320 blocks, heavy
// first, all co-resident at 2 blocks/CU (LDS 74.2 KB). exp2-domain softmax;
// masking skipped on wave-uniformly-full chunks. Partials in log2 domain.
// ---------------------------------------------------------------------------
__global__ __launch_bounds__(256) void attn_part(
    const short* __restrict__ qb, const short* __restrict__ kb,
    const short* __restrict__ vtb, float* __restrict__ po,
    float* __restrict__ pm, float* __restrict__ pl) {
  __shared__ alignas(16) char smem[74240];
  short* Ks0 = (short*)smem;               // [64][128] bf16 swizzled
  short* Ks1 = (short*)(smem + 16384);
  short* Vt0 = (short*)(smem + 32768);     // [128][64] bf16 swizzled
  short* Vt1 = (short*)(smem + 49152);
  short* Pt  = (short*)(smem + 65536);     // 4 waves x [16][68] bf16

  const int tid = threadIdx.x;
  const int wv = tid >> 6, lane = tid & 63;
  const int ln = lane & 15, quad = lane >> 4;
  const int b = blockIdx.x / 40;
  const int rr = 39 - (blockIdx.x % 40);   // heavy segments first
  // decode rr -> (j, s): tile group G = j>>2 has nseg = G+1; base = 2G(G+1)
  const int G = (rr >= 24) ? 3 : (rr >= 12) ? 2 : (rr >= 4) ? 1 : 0;
  const int local = rr - 2 * G * (G + 1);
  const int j = 4 * G + local / (G + 1);
  const int s = local - (local / (G + 1)) * (G + 1);
  const int sid = b * 40 + rr;             // partial storage slot
  const int q0 = j * 128;
  const int nchunks = min(8, 2 * j + 2 - 8 * s);

  short* myP = Pt + wv * (16 * 68);

  bf16x8 qfr[2][4];  // this wave's 32 queries (2 x 16), B-operand layout
#pragma unroll
  for (int m = 0; m < 2; ++m)
#pragma unroll
    for (int kk = 0; kk < 4; ++kk)
      qfr[m][kk] = *(const bf16x8*)(qb +
          (size_t)(b * T_ + q0 + wv * 32 + m * 16 + ln) * H_ + kk * 32 + quad * 8);

  f32x4 oacc[2][8];  // O^T per subtile: h = ht*16+quad*4+r, q = ln
#pragma unroll
  for (int m = 0; m < 2; ++m)
#pragma unroll
    for (int ht = 0; ht < 8; ++ht) oacc[m][ht] = (f32x4){0.f, 0.f, 0.f, 0.f};

  float m_run[2] = {-INFINITY, -INFINITY};
  float l_run[2] = {0.f, 0.f};

  auto stageK = [&](short* dst, int s0) {
#pragma unroll
    for (int jj = 0; jj < 4; ++jj) {
      const int rb = wv * 16 + jj * 4;       // 16 rows per wave
      const int r = rb + (lane >> 4);
      const int gp = (lane & 15) ^ (r & 7);
      gll16(kb + (size_t)(b * T_ + s0 + r) * H_ + gp * 8, (char*)dst + rb * 256);
    }
  };
  auto stageV = [&](short* dst, int s0) {
#pragma unroll
    for (int jj = 0; jj < 4; ++jj) {
      const int hb = wv * 32 + jj * 8;       // 32 rows per wave
      const int h = hb + (lane >> 3);
      const int gp = (lane & 7) ^ (h & 7);
      gll16(vtb + (size_t)(b * H_ + h) * T_ + s0 + gp * 8, (char*)dst + hb * 128);
    }
  };

  stageK(Ks0, 8 * s * 64);  // prologue: first chunk of this segment
  stageV(Vt0, 8 * s * 64);

  for (int ch = 0; ch < nchunks; ++ch) {
    const int s0 = (8 * s + ch) * 64;
    const int cur = ch & 1;
    __syncthreads();  // drains gll for buf[cur]; other buffer free to restage
    if (ch + 1 < nchunks) {
      stageK(cur ? Ks0 : Ks1, s0 + 64);
      stageV(cur ? Vt0 : Vt1, s0 + 64);
    }
    const short* Kc = cur ? Ks1 : Ks0;
    const short* Vc = cur ? Vt1 : Vt0;

    // S^T = K * Q^T : 16 K-frag reads shared by 2 subtiles -> 32 MFMAs
    f32x4 sacc[2][4];
#pragma unroll
    for (int m = 0; m < 2; ++m)
#pragma unroll
      for (int t = 0; t < 4; ++t) sacc[m][t] = (f32x4){0.f, 0.f, 0.f, 0.f};
#pragma unroll
    for (int kk = 0; kk < 4; ++kk) {
#pragma unroll
      for (int t = 0; t < 4; ++t) {
        const int krow = t * 16 + ln;
        bf16x8 kf = *(bf16x8*)&Kc[krow * 128 + (((kk * 4 + quad) ^ (ln & 7)) * 8)];
#pragma unroll
        for (int m = 0; m < 2; ++m)
          sacc[m][t] = __builtin_amdgcn_mfma_f32_16x16x32_bf16(kf, qfr[m][kk], sacc[m][t], 0, 0, 0);
      }
    }

    // wave-local online softmax (log2 domain), per 16-q subtile
    const bool needMask = (s0 + 63 > q0 + wv * 32);  // wave-uniform
    float p[2][4][4], alpha[2];
#pragma unroll
    for (int m = 0; m < 2; ++m) {
      const int qg = q0 + wv * 32 + m * 16 + ln;
      float sv[4][4];
      float mc = -INFINITY;
#pragma unroll
      for (int t = 0; t < 4; ++t)
#pragma unroll
        for (int r = 0; r < 4; ++r) {
          float scv = sacc[m][t][r] * SCALE2;
          if (needMask) {
            const int key = s0 + t * 16 + quad * 4 + r;
            scv = (key <= qg) ? scv : -INFINITY;
          }
          sv[t][r] = scv;
          mc = fmaxf(mc, scv);
        }
      mc = fmaxf(mc, __shfl_xor(mc, 16));
      mc = fmaxf(mc, __shfl_xor(mc, 32));
      const float mnew = fmaxf(m_run[m], mc);
      alpha[m] = exp2f(m_run[m] - mnew);
      float lc = 0.f;
#pragma unroll
      for (int t = 0; t < 4; ++t)
#pragma unroll
        for (int r = 0; r < 4; ++r) {
          p[m][t][r] = exp2f(sv[t][r] - mnew);
          lc += p[m][t][r];
        }
      lc += __shfl_xor(lc, 16);
      lc += __shfl_xor(lc, 32);
      l_run[m] = l_run[m] * alpha[m] + lc;
      m_run[m] = mnew;
    }

    // PV per subtile (single P scratch per wave, lgkm-ordered reuse)
#pragma unroll
    for (int m = 0; m < 2; ++m) {
#pragma unroll
      for (int ht = 0; ht < 8; ++ht)
#pragma unroll
        for (int r = 0; r < 4; ++r) oacc[m][ht][r] *= alpha[m];
#pragma unroll
      for (int t = 0; t < 4; ++t) {
        *(unsigned int*)&myP[ln * 68 + t * 16 + quad * 4 + 0] = pk2(p[m][t][0], p[m][t][1]);
        *(unsigned int*)&myP[ln * 68 + t * 16 + quad * 4 + 2] = pk2(p[m][t][2], p[m][t][3]);
      }
#pragma unroll
      for (int kk2 = 0; kk2 < 2; ++kk2) {
        bf16x8 pf = *(bf16x8*)&myP[ln * 68 + kk2 * 32 + quad * 8];
#pragma unroll
        for (int ht = 0; ht < 8; ++ht) {
          const int hrow = ht * 16 + ln;
          bf16x8 vf = *(bf16x8*)&Vc[hrow * 64 + (((kk2 * 4 + quad) ^ (ln & 7)) * 8)];
          oacc[m][ht] = __builtin_amdgcn_mfma_f32_16x16x32_bf16(vf, pf, oacc[m][ht], 0, 0, 0);
        }
      }
    }
  }

  // write partials: m (log2 domain), l, un-normalized O via LDS transpose
  if (quad == 0) {
#pragma unroll
    for (int m = 0; m < 2; ++m) {
      pm[(size_t)sid * 128 + wv * 32 + m * 16 + ln] = m_run[m];
      pl[(size_t)sid * 128 + wv * 32 + m * 16 + ln] = l_run[m];
    }
  }
  __syncthreads();  // Ks/Vt dead; reuse for Ot
  float* Ot = (float*)smem;  // [128][132] f32 = 67.6 KB (fits in 74240)
#pragma unroll
  for (int m = 0; m < 2; ++m)
#pragma unroll
    for (int ht = 0; ht < 8; ++ht)
      *(f32x4*)&Ot[(wv * 32 + m * 16 + ln) * 132 + ht * 16 + quad * 4] = oacc[m][ht];
  __syncthreads();
  float* dst = po + (size_t)sid * 16384;
#pragma unroll
  for (int i = 0; i < 16; ++i) {
    int slot2 = tid + i * 256;            // 4096 float4 slots: 128 q x 32
    int r2 = slot2 >> 5, c2 = slot2 & 31;
    *(f32x4*)(dst + r2 * 128 + c2 * 4) = *(f32x4*)&Ot[r2 * 132 + c2 * 4];
  }
}

// ---------------------------------------------------------------------------
// Attention part 2: combine <=4 partials per (b, 128q-tile) with max-rescale
// (log2 domain). 256 blocks x 256 thr; block = half a q-tile (64 q).
// ---------------------------------------------------------------------------
__global__ __launch_bounds__(256) void attn_reduce(
    const float* __restrict__ po, const float* __restrict__ pm,
    const float* __restrict__ pl, float* __restrict__ out) {
  const int b = blockIdx.x >> 5;
  const int rem = blockIdx.x & 31;
  const int j = rem >> 1, half = rem & 1;
  const int G = j >> 2;
  const int nseg = G + 1;
  const int sid0 = b * 40 + 2 * G * (G + 1) + (j - 4 * G) * nseg;
  const int tid = threadIdx.x;
  const int q = half * 64 + (tid >> 2), hq = tid & 3;

  float m2[4], l[4], a[4];
  float M2 = -INFINITY;
  for (int s2 = 0; s2 < nseg; ++s2) {
    m2[s2] = pm[(size_t)(sid0 + s2) * 128 + q];
    l[s2] = pl[(size_t)(sid0 + s2) * 128 + q];
    M2 = fmaxf(M2, m2[s2]);
  }
  float lsum = 0.f;
  for (int s2 = 0; s2 < nseg; ++s2) {
    a[s2] = exp2f(m2[s2] - M2);
    lsum += a[s2] * l[s2];
  }
  f32x4 acc[8];
#pragma unroll
  for (int i = 0; i < 8; ++i) acc[i] = (f32x4){0.f, 0.f, 0.f, 0.f};
  for (int s2 = 0; s2 < nseg; ++s2) {
    const float* src = po + (size_t)(sid0 + s2) * 16384 + q * 128 + hq * 32;
    const float as = a[s2];
#pragma unroll
    for (int i = 0; i < 8; ++i) {
      f32x4 v = *(const f32x4*)(src + i * 4);
#pragma unroll
      for (int c = 0; c < 4; ++c) acc[i][c] += as * v[c];
    }
  }
  const float inv = 1.0f / lsum;
  float* o = out + ((size_t)(b * T_ + j * 128 + q)) * H_ + hq * 32;
#pragma unroll
  for (int i = 0; i < 8; ++i) {
    f32x4 v;
#pragma unroll
    for (int c = 0; c < 4; ++c) v[c] = acc[i][c] * inv;
    *(f32x4*)(o + i * 4) = v;
  }
}

// ---------------------------------------------------------------------------
extern "C" void kernel_launch(void* const* d_in, const int* in_sizes, int n_in,
                              void* d_out, int out_size, void* d_ws, size_t ws_size,
                              hipStream_t stream) {
  const float* x  = (const float*)d_in[0];
  const float* Wq = (const float*)d_in[1];
  const float* Wk = (const float*)d_in[2];
  const float* Wv = (const float*)d_in[3];
  float* out = (float*)d_out;

  char* ws = (char*)d_ws;
  short* qb  = (short*)(ws);                // 4 MB   q  bf16 [BT][128]
  short* kb  = (short*)(ws + 4194304);      // 4 MB   k  bf16 [BT][128]
  short* vtb = (short*)(ws + 8388608);      // 4 MB   v^T bf16 [B][128][T]
  short* Wt  = (short*)(ws + 12582912);     // 0.75 MB W^T bf16 [3][128][1024]
  float* po  = (float*)(ws + 14680064);     // 20 MB  partial O (320 x 64 KB)
  float* pm  = (float*)(ws + 35651584);     // 160 KB partial m (log2 domain)
  float* pl  = (float*)(ws + 35915776);     // 160 KB partial l

  wcvt_kernel<<<dim3(D_ / 64, 3), 256, 0, stream>>>(Wq, Wk, Wv, Wt);
  proj_kernel<<<dim3(BT / 64, 3), 256, 0, stream>>>(x, Wt, qb, kb, vtb);
  attn_part<<<dim3(8 * 40), 256, 0, stream>>>(qb, kb, vtb, po, pm, pl);
  attn_reduce<<<dim3(8 * 32), 256, 0, stream>>>(po, pm, pl, out);
}